// Round 10
// baseline (137.660 us; speedup 1.0000x reference)
//
#include <hip/hip_runtime.h>
#include <math.h>

constexpr int BLOCK = 256;   // 3 consumer waves + 1 producer wave
constexpr int NCONS = 3;     // consumer waves per block
constexpr int NSLOT = 3;     // ring slots per consumer (2 rounds of slack)

// address-space-typed pointers for global_load_lds
typedef __attribute__((address_space(3))) uint32_t lds_u32_t;
typedef __attribute__((address_space(1))) const uint32_t glb_u32_t;

#define FENCE() asm volatile("" ::: "memory")
// raw barrier (m201 pattern): does NOT drain vmcnt like __syncthreads;
// FENCEs stop the compiler moving LDS/global ops across it.
__device__ __forceinline__ void BAR() {
    FENCE(); __builtin_amdgcn_s_barrier(); FENCE();
}

// issue one 64-matrix tile (2304 B) into LDS: 16/16/4 B per lane.
// LDS dest is wave-uniform base + lane*size (m104/m108) -> linear layout.
__device__ __forceinline__ void issue_tile_loads(
    const float* __restrict__ rot, long long tile, int lane, float* buf)
{
    const char* g = (const char*)rot + (size_t)tile * 2304;
    __builtin_amdgcn_global_load_lds((glb_u32_t*)(g + (size_t)lane * 16),
                                     (lds_u32_t*)buf, 16, 0, 0);
    __builtin_amdgcn_global_load_lds((glb_u32_t*)(g + 1024 + (size_t)lane * 16),
                                     (lds_u32_t*)(buf + 256), 16, 0, 0);
    __builtin_amdgcn_global_load_lds((glb_u32_t*)(g + 2048 + (size_t)lane * 4),
                                     (lds_u32_t*)(buf + 512), 4, 0, 0);
}

// ---- hybrid-scaled polar core (r8 math, verified absmax 0.0039) ---------
// it0 Frobenius-scaled, it1-4 determinant-scaled (Byers), final unscaled
// polish. det sign via f64 det(R) only (det(M)>0 folded out).
__device__ __forceinline__ void polar_core_h(
    const float r0, const float r1, const float r2,
    const float r3, const float r4, const float r5,
    const float r6, const float r7, const float r8,
    const float m0, const float m1, const float m2,
    const float m3, const float m4, const float m5,
    const float m6, const float m7, const float m8,
    float& x0, float& x1, float& x2,
    float& x3, float& x4, float& x5,
    float& x6, float& x7, float& x8)
{
    const double dR = (double)r0*((double)r4*r8-(double)r5*r7)
                    - (double)r1*((double)r3*r8-(double)r5*r6)
                    + (double)r2*((double)r3*r7-(double)r4*r6);
    const float detA = (float)dR;

    x0=fmaf(r0,m0,fmaf(r1,m3,r2*m6));
    x1=fmaf(r0,m1,fmaf(r1,m4,r2*m7));
    x2=fmaf(r0,m2,fmaf(r1,m5,r2*m8));
    x3=fmaf(r3,m0,fmaf(r4,m3,r5*m6));
    x4=fmaf(r3,m1,fmaf(r4,m4,r5*m7));
    x5=fmaf(r3,m2,fmaf(r4,m5,r5*m8));
    x6=fmaf(r6,m0,fmaf(r7,m3,r8*m6));
    x7=fmaf(r6,m1,fmaf(r7,m4,r8*m7));
    x8=fmaf(r6,m2,fmaf(r7,m5,r8*m8));

    // it0: Frobenius-scaled
    {
        const float c0=fmaf(x4,x8,-x5*x7), c1=fmaf(x5,x6,-x3*x8), c2=fmaf(x3,x7,-x4*x6);
        const float c3=fmaf(x2,x7,-x1*x8), c4=fmaf(x0,x8,-x2*x6), c5=fmaf(x1,x6,-x0*x7);
        const float c6=fmaf(x1,x5,-x2*x4), c7=fmaf(x2,x3,-x0*x5), c8=fmaf(x0,x4,-x1*x3);
        const float adet = fmaxf(fabsf(detA), 1e-30f);
        float nX2, nC2;
        { const float a=fmaf(x1,x1,x0*x0), b=fmaf(x3,x3,x2*x2),
                      e=fmaf(x5,x5,x4*x4), d=fmaf(x7,x7,x6*x6);
          nX2=(a+b)+(e+fmaf(x8,x8,d)); }
        { const float a=fmaf(c1,c1,c0*c0), b=fmaf(c3,c3,c2*c2),
                      e=fmaf(c5,c5,c4*c4), d=fmaf(c7,c7,c6*c6);
          nC2=(a+b)+(e+fmaf(c8,c8,d)); }
        const float h  = __builtin_amdgcn_rsqf(adet);
        const float pr = __builtin_amdgcn_sqrtf(__builtin_amdgcn_sqrtf(
                             nC2*__builtin_amdgcn_rcpf(nX2)));
        const float qr = __builtin_amdgcn_rcpf(pr);
        const float s = 0.5f*pr*h;
        const float t = copysignf(0.5f*qr*h, detA);
        x0=fmaf(s,x0,t*c0); x1=fmaf(s,x1,t*c1); x2=fmaf(s,x2,t*c2);
        x3=fmaf(s,x3,t*c3); x4=fmaf(s,x4,t*c4); x5=fmaf(s,x5,t*c5);
        x6=fmaf(s,x6,t*c6); x7=fmaf(s,x7,t*c7); x8=fmaf(s,x8,t*c8);
    }
    // it1..4: determinant-scaled (no norms)
    #pragma unroll
    for (int it = 0; it < 4; ++it) {
        const float c0=fmaf(x4,x8,-x5*x7), c1=fmaf(x5,x6,-x3*x8), c2=fmaf(x3,x7,-x4*x6);
        const float c3=fmaf(x2,x7,-x1*x8), c4=fmaf(x0,x8,-x2*x6), c5=fmaf(x1,x6,-x0*x7);
        const float c6=fmaf(x1,x5,-x2*x4), c7=fmaf(x2,x3,-x0*x5), c8=fmaf(x0,x4,-x1*x3);
        const float det = fmaf(x0,c0,fmaf(x1,c1,x2*c2));
        const float adet = fmaxf(fabsf(det), 1e-30f);
        const float mu = __builtin_amdgcn_exp2f(
                             -0.33333333f*__builtin_amdgcn_logf(adet));
        const float s = 0.5f*mu;
        const float t = copysignf(0.5f*__builtin_amdgcn_rcpf(mu*adet), det);
        x0=fmaf(s,x0,t*c0); x1=fmaf(s,x1,t*c1); x2=fmaf(s,x2,t*c2);
        x3=fmaf(s,x3,t*c3); x4=fmaf(s,x4,t*c4); x5=fmaf(s,x5,t*c5);
        x6=fmaf(s,x6,t*c6); x7=fmaf(s,x7,t*c7); x8=fmaf(s,x8,t*c8);
    }
    // final unscaled polish
    {
        const float c0=fmaf(x4,x8,-x5*x7), c1=fmaf(x5,x6,-x3*x8), c2=fmaf(x3,x7,-x4*x6);
        const float c3=fmaf(x2,x7,-x1*x8), c4=fmaf(x0,x8,-x2*x6), c5=fmaf(x1,x6,-x0*x7);
        const float c6=fmaf(x1,x5,-x2*x4), c7=fmaf(x2,x3,-x0*x5), c8=fmaf(x0,x4,-x1*x3);
        const float det = fmaf(x0,c0,fmaf(x1,c1,x2*c2));
        const float t = 0.5f*__builtin_amdgcn_rcpf(det);
        x0=fmaf(0.5f,x0,t*c0); x1=fmaf(0.5f,x1,t*c1); x2=fmaf(0.5f,x2,t*c2);
        x3=fmaf(0.5f,x3,t*c3); x4=fmaf(0.5f,x4,t*c4); x5=fmaf(0.5f,x5,t*c5);
        x6=fmaf(0.5f,x6,t*c6); x7=fmaf(0.5f,x7,t*c7); x8=fmaf(0.5f,x8,t*c8);
    }
}

// r14: PRODUCER/CONSUMER WAVE SPECIALIZATION (the one untried structural
// class; named by the µarch notes as the path past the drain-coupling).
// Evidence r0-r13: dur == V(~20-24us) + C(~25-27us) invariant under
// barriers, depth 1/2/3, ILP, skew, persistence. Common feature of all:
// the SAME wave computes and waits on its own loads -> its compute is
// dead time for its memory stream and vice versa; chip-wide the pipes
// alternate at ~50/50 (measured). Fix: per block, wave 3 = pure producer
// (issues all global_load_lds, counted vmcnt with one full round of
// slack, no polar core); waves 0-2 = pure consumers (LDS->compute->store;
// NEVER wait on a vmem load — their stores ride a separate per-wave
// vmcnt). Handoff: 3-slot ring per consumer + one RAW s_barrier per
// round (no vmcnt drain; m201). Visibility = m97 argument: the only wave
// with outstanding loads drains them (counted) before the barrier.
// Ring safety: round r consumer reads slot r%3; producer concurrently
// fills slot (r+2)%3 != r%3; slot r%3 is refilled by L(r+3) issued in
// round r+1, after the consumer's end-of-round-r barrier. Barrier counts
// uniform across all 4 waves (1 prologue + nrounds) -> no deadlock.
__global__ __launch_bounds__(BLOCK) void polar3x3_kernel(
    const float* __restrict__ rot,
    const float* __restrict__ mat,
    float* __restrict__ outq,
    float* __restrict__ logdet,
    int N)
{
    __shared__ float lds[NCONS * NSLOT * 576];   // 20736 B -> 7 blocks/CU
    const int lane = threadIdx.x & 63;
    const int wave = threadIdx.x >> 6;
    const int NT = N >> 6;                                   // full tiles
    const long long CW = (long long)gridDim.x * NCONS;       // total consumers
    const int nrounds = (int)(((long long)NT + CW - 1) / CW);

    // uniform 'mat' + full drain so the producer's vmcnt ledger starts at 0
    const float m0=mat[0], m1=mat[1], m2=mat[2], m3=mat[3], m4=mat[4],
                m5=mat[5], m6=mat[6], m7=mat[7], m8=mat[8];
    asm volatile("s_waitcnt vmcnt(0) lgkmcnt(0)" ::: "memory");

    if (wave == NCONS) {
        // ============================ PRODUCER ===========================
        // L(r) = 9 loads (3 consumers x 3) into slot r%NSLOT of each
        // consumer's ring. Prologue: issue L(0),L(1); drain L(0); barrier.
        for (int r = 0; r < 2; ++r) {
            for (int c = 0; c < NCONS; ++c) {
                long long t = (long long)r * CW + (long long)blockIdx.x * NCONS + c;
                if (t >= NT) t = 0;                          // dummy, keeps count regular
                issue_tile_loads(rot, t, lane,
                                 &lds[(c * NSLOT + (r % NSLOT)) * 576]);
            }
        }
        asm volatile("s_waitcnt vmcnt(9)" ::: "memory");     // L(0) landed
        BAR();                                               // release round 0
        for (int r = 0; r < nrounds; ++r) {
            for (int c = 0; c < NCONS; ++c) {                // issue L(r+2)
                long long t = (long long)(r + 2) * CW + (long long)blockIdx.x * NCONS + c;
                if (t >= NT) t = 0;
                issue_tile_loads(rot, t, lane,
                                 &lds[(c * NSLOT + ((r + 2) % NSLOT)) * 576]);
            }
            // outstanding = L(r+1)(9) + L(r+2)(9); drain L(r+1) only.
            asm volatile("s_waitcnt vmcnt(9)" ::: "memory");
            BAR();                                           // release round r+1
        }
    } else {
        // ============================ CONSUMER ===========================
        const int c = wave;
        float* ring = &lds[c * NSLOT * 576];
        BAR();                                               // round-0 data ready
        for (int r = 0; r < nrounds; ++r) {
            const long long t = (long long)r * CW + (long long)blockIdx.x * NCONS + c;
            if (t < NT) {
                float* buf = ring + (r % NSLOT) * 576;
                // stride-9 b32 reads: 2-way bank alias = free (m136)
                const float* rd = &buf[lane * 9];
                const float r0=rd[0],r1=rd[1],r2=rd[2],r3=rd[3],r4=rd[4],
                            r5=rd[5],r6=rd[6],r7=rd[7],r8=rd[8];
                float x0,x1,x2,x3,x4,x5,x6,x7,x8;
                polar_core_h(r0,r1,r2,r3,r4,r5,r6,r7,r8,
                             m0,m1,m2,m3,m4,m5,m6,m7,m8,
                             x0,x1,x2,x3,x4,x5,x6,x7,x8);
                // own-slot write; wave-lockstep -> lgkmcnt(0) suffices
                float* w = &buf[lane * 9];
                w[0]=x0; w[1]=x1; w[2]=x2; w[3]=x3; w[4]=x4;
                w[5]=x5; w[6]=x6; w[7]=x7; w[8]=x8;
                asm volatile("s_waitcnt lgkmcnt(0)" ::: "memory");
                // stage out: lane-contiguous b128 reads + coalesced stores.
                // Stores are fire-and-forget on THIS wave's vmcnt — the
                // consumer never waits on vmem.
                const long long mb = t * 64;
                float* gdst = outq + mb * 9;
                const float4* l4 = (const float4*)buf;
                float4* g4 = (float4*)gdst;
                g4[lane]         = l4[lane];
                g4[64 + lane]    = l4[64 + lane];
                gdst[512 + lane] = buf[512 + lane];
                logdet[mb + lane] = 0.0f;
            }
            BAR();                                           // end of round r
        }
    }

    // ---- remainder matrices (N % 64 != 0; never taken at N=2M) ----------
    const int rem = N - NT * 64;
    if (rem > 0 && blockIdx.x == 0 && wave == 0) {
        const long long tb = (long long)NT * 64;
        const bool act = lane < rem;
        float r0=1.f,r1=0.f,r2=0.f,r3=0.f,r4=1.f,r5=0.f,r6=0.f,r7=0.f,r8=1.f;
        const float* gsrc = rot + (tb + lane) * 9;
        if (act) { r0=gsrc[0];r1=gsrc[1];r2=gsrc[2];r3=gsrc[3];r4=gsrc[4];
                   r5=gsrc[5];r6=gsrc[6];r7=gsrc[7];r8=gsrc[8]; }
        float x0,x1,x2,x3,x4,x5,x6,x7,x8;
        polar_core_h(r0,r1,r2,r3,r4,r5,r6,r7,r8,
                     m0,m1,m2,m3,m4,m5,m6,m7,m8,
                     x0,x1,x2,x3,x4,x5,x6,x7,x8);
        if (act) {
            float* gdst = outq + (tb + lane) * 9;
            gdst[0]=x0; gdst[1]=x1; gdst[2]=x2; gdst[3]=x3; gdst[4]=x4;
            gdst[5]=x5; gdst[6]=x6; gdst[7]=x7; gdst[8]=x8;
            logdet[tb + lane] = 0.0f;
        }
    }
}

extern "C" void kernel_launch(void* const* d_in, const int* in_sizes, int n_in,
                              void* d_out, int out_size, void* d_ws, size_t ws_size,
                              hipStream_t stream) {
    const float* rot = (const float*)d_in[0];
    const float* mat = (const float*)d_in[1];
    float* out = (float*)d_out;
    const int N = in_sizes[0] / 9;                 // 2,000,000
    float* logdet = out + (long long)N * 9;        // outputs concatenated flat
    const int NT = N >> 6;
    // 1792 blocks = 7 blocks/CU (LDS-limited: 7 x 20736 B = 142 KiB <= 160
    // KiB; 1792 threads/CU <= 2048). 5376 consumer waves -> 6 rounds.
    long long nb = ((long long)NT + NCONS - 1) / NCONS;
    if (nb > 1792) nb = 1792;
    if (nb < 1) nb = 1;
    polar3x3_kernel<<<(int)nb, BLOCK, 0, stream>>>(rot, mat, out, logdet, N);
}